// Round 7
// baseline (516.328 us; speedup 1.0000x reference)
//
#include <hip/hip_runtime.h>

// Problem constants
#define KC   1024        // codebook size
#define DD   64          // code dim
#define NR   65536       // total rows (16*4096)

#define DECAY     0.99f
#define ONEM      0.01f
#define EPSV     1e-5f

// d_out layout (floats), in reference return order:
#define OFF_ZQ    0
#define OFF_LOSS  4194304
#define OFF_IDX   4194305
#define OFF_NCB   4259841
#define OFF_NECS  4325377
#define OFF_NEW   4326401

// Scratch aliases inside d_out (zeroed by prep, consumed+overwritten later):
//   cluster counts -> OFF_NECS (1024); cluster sums -> OFF_NEW (65536);
//   SSE -> OFF_LOSS (1). d_ws: 1024-float stabilized denominator table.

typedef __attribute__((ext_vector_type(4))) float f32x4;

// Zero the atomic-accumulator regions. 65 blocks x 1024.
__global__ void vq_prep(float* __restrict__ out) {
    const int tid = blockIdx.x * blockDim.x + threadIdx.x;
    if (tid < 65536)      out[OFF_NEW + tid] = 0.0f;           // cluster sums
    else if (tid < 66560) out[OFF_NECS + (tid - 65536)] = 0.0f; // counts
    if (tid == 0)         out[OFF_LOSS] = 0.0f;                 // SSE
}

// 256 blocks x 1024 threads. Thread t <-> code t (whole codebook per block).
// Each thread holds its code's 64 floats in VGPRs (volatile-asm loads:
// remat-proof; rounds 1-3 showed C-level loads get rematerialized).
// Block owns 256 rows; per row, z is block-uniform -> scalar loads that are
// sL1-hot (all 16 waves read the same row). Per row: 64 reg-resident FMAs
// + 6-level shfl_xor argmin (first-index tiebreak) + lane0 candidate store.
__global__ __launch_bounds__(1024, 2) void vq_main(const float* __restrict__ z,
                                                   const float* __restrict__ cb,
                                                   float* __restrict__ out) {
    const int t    = threadIdx.x;        // code id
    const int lane = t & 63;
    const int wid  = t >> 6;
    const int rowbase = blockIdx.x * 256;

    __shared__ float s_cd[16 * 256];     // per-wave candidate dist [w][row]
    __shared__ int   s_ci[16 * 256];     // per-wave candidate idx  [w][row]
    __shared__ int   s_final[256];
    __shared__ float s_red[1024];

    // --- load my code vector into 64 pinned VGPRs ---
    f32x4 c[16];
    const float* cbase = cb + (size_t)t * 64;
    #pragma unroll
    for (int j = 0; j < 16; ++j) {
        asm volatile("global_load_dwordx4 %0, %1, off"
                     : "=v"(c[j]) : "v"(cbase + j * 4) : "memory");
    }
    asm volatile("s_waitcnt vmcnt(0)" ::: "memory");
    __builtin_amdgcn_sched_barrier(0);

    // ||c||^2 from registers (prep's cc table deleted).
    float cn = 0.f;
    #pragma unroll
    for (int j = 0; j < 16; ++j) {
        cn = fmaf(c[j].x, c[j].x, cn);
        cn = fmaf(c[j].y, c[j].y, cn);
        cn = fmaf(c[j].z, c[j].z, cn);
        cn = fmaf(c[j].w, c[j].w, cn);
    }

    // --- row loop: 256 rows per block ---
    for (int ri = 0; ri < 256; ++ri) {
        const float4* zr4 =
            reinterpret_cast<const float4*>(z + (size_t)(rowbase + ri) * 64);
        float a[4] = {0.f, 0.f, 0.f, 0.f};
        #pragma unroll
        for (int j = 0; j < 16; ++j) {   // z quads: uniform -> s_load_dwordx4
            const float4 zq = zr4[j];
            a[j & 3] = fmaf(zq.x, c[j].x, a[j & 3]);
            a[j & 3] = fmaf(zq.y, c[j].y, a[j & 3]);
            a[j & 3] = fmaf(zq.z, c[j].z, a[j & 3]);
            a[j & 3] = fmaf(zq.w, c[j].w, a[j & 3]);
        }
        // score = ||c||^2 - 2*dot; row term constant over codes -> same argmin.
        float bd = fmaf(-2.f, (a[0] + a[1]) + (a[2] + a[3]), cn);
        int   bi = t;
        // wave argmin, exact first-index (lowest code) tiebreak
        #pragma unroll
        for (int m = 32; m >= 1; m >>= 1) {
            const float od = __shfl_xor(bd, m);
            const int   oi = __shfl_xor(bi, m);
            if (od < bd || (od == bd && oi < bi)) { bd = od; bi = oi; }
        }
        if (lane == 0) { s_cd[wid * 256 + ri] = bd; s_ci[wid * 256 + ri] = bi; }
    }
    __syncthreads();

    // --- cross-wave finish: thread r owns row r (waves ascend in code space) ---
    if (t < 256) {
        float bd = s_cd[t];
        int   bi = s_ci[t];
        #pragma unroll
        for (int w = 1; w < 16; ++w) {
            const float d = s_cd[w * 256 + t];
            const int   i = s_ci[w * 256 + t];
            if (d < bd || (d == bd && i < bi)) { bd = d; bi = i; }
        }
        s_final[t] = bi;
        out[OFF_IDX + rowbase + t] = (float)bi;
        atomicAdd(&out[OFF_NECS + bi], 1.0f);        // cluster count
    }
    __syncthreads();

    // --- phase 2: z_q write + commitment SSE + cluster-sum atomics ---
    // Block tile = 256 rows * 16 float4 = 4096 float4s; 4 per thread.
    float sse = 0.f;
    const float4* zb4 = reinterpret_cast<const float4*>(z) + (size_t)blockIdx.x * 4096;
    float4*       qb  = reinterpret_cast<float4*>(out + OFF_ZQ) + (size_t)blockIdx.x * 4096;
    const float4* cb4 = reinterpret_cast<const float4*>(cb);
    #pragma unroll
    for (int j = 0; j < 4; ++j) {
        const int f  = t + 1024 * j;
        const int r  = f >> 4;
        const int fc = f & 15;
        const int gk = s_final[r];
        const float4 zv = zb4[f];
        const float4 cv = cb4[gk * 16 + fc];
        qb[f] = cv;                      // z_q_st == z_q numerically
        const float e0 = zv.x - cv.x, e1 = zv.y - cv.y;
        const float e2 = zv.z - cv.z, e3 = zv.w - cv.w;
        sse += e0 * e0 + e1 * e1 + e2 * e2 + e3 * e3;
        float* sp = out + OFF_NEW + gk * 64 + fc * 4;
        atomicAdd(sp + 0, zv.x);
        atomicAdd(sp + 1, zv.y);
        atomicAdd(sp + 2, zv.z);
        atomicAdd(sp + 3, zv.w);
    }

    s_red[t] = sse;
    __syncthreads();
    for (int off = 512; off > 0; off >>= 1) {
        if (t < off) s_red[t] += s_red[t + off];
        __syncthreads();
    }
    if (t == 0) atomicAdd(&out[OFF_LOSS], s_red[0]);
}

// One block, 1024 threads: EMA cluster-size update + n-reduction + den table.
__global__ __launch_bounds__(1024) void vq_final_a(const float* __restrict__ ema_cs,
                                                   float* __restrict__ out,
                                                   float* __restrict__ den) {
    const int k = threadIdx.x;
    const float cnt  = out[OFF_NECS + k];
    const float necs = DECAY * ema_cs[k] + ONEM * cnt;

    __shared__ float s_red[1024];
    s_red[k] = necs;
    __syncthreads();
    for (int off = 512; off > 0; off >>= 1) {
        if (k < off) s_red[k] += s_red[k + off];
        __syncthreads();
    }
    const float n = s_red[0];

    out[OFF_NECS + k] = necs;
    den[k] = (necs + EPSV) / (n + (float)KC * EPSV) * n;
    if (k == 0) out[OFF_LOSS] = 0.25f * out[OFF_LOSS] * (1.f / 4194304.f);
}

// 64 blocks x 1024 threads: EMA w update + codebook normalization.
__global__ __launch_bounds__(1024) void vq_final_b(const float* __restrict__ ema_w,
                                                   const float* __restrict__ den,
                                                   float* __restrict__ out) {
    const int e = blockIdx.x * 1024 + threadIdx.x;      // 0..65535, coalesced
    const float s  = out[OFF_NEW + e];                  // raw cluster sum
    const float ew = DECAY * ema_w[e] + ONEM * s;
    out[OFF_NEW + e] = ew;                              // new_ew
    out[OFF_NCB + e] = ew / den[e >> 6];                // new_codebook
}

extern "C" void kernel_launch(void* const* d_in, const int* in_sizes, int n_in,
                              void* d_out, int out_size, void* d_ws, size_t ws_size,
                              hipStream_t stream) {
    const float* z   = (const float*)d_in[0];
    const float* cb  = (const float*)d_in[1];
    const float* ecs = (const float*)d_in[2];
    const float* ew  = (const float*)d_in[3];
    float* out = (float*)d_out;
    float* den = (float*)d_ws;      // 1024 floats of scratch

    vq_prep   <<<65,  1024, 0, stream>>>(out);
    vq_main   <<<256, 1024, 0, stream>>>(z, cb, out);
    vq_final_a<<<1,   1024, 0, stream>>>(ecs, out, den);
    vq_final_b<<<64,  1024, 0, stream>>>(ew, den, out);
}

// Round 8
// 300.881 us; speedup vs baseline: 1.7161x; 1.7161x over previous
//
#include <hip/hip_runtime.h>

// Problem constants
#define KC   1024        // codebook size
#define DD   64          // code dim
#define NR   65536       // total rows (16*4096)

#define DECAY     0.99f
#define ONEM      0.01f
#define EPSV      1e-5f

// d_out layout (floats), in reference return order:
#define OFF_ZQ    0
#define OFF_LOSS  4194304
#define OFF_IDX   4194305
#define OFF_NCB   4259841
#define OFF_NECS  4325377
#define OFF_NEW   4326401

// Scratch aliases inside d_out (zeroed/filled by prep, consumed later):
//   cluster counts -> OFF_NECS (1024); cluster sums -> OFF_NEW (65536);
//   SSE -> OFF_LOSS (1); ||c||^2 table -> first 1024 floats of OFF_NCB.
// d_ws: 1024-float stabilized denominator table (final_a -> final_b).

__global__ void vq_prep(const float* __restrict__ cb, float* __restrict__ out) {
    int tid = blockIdx.x * blockDim.x + threadIdx.x;
    if (tid < 65536) out[OFF_NEW + tid] = 0.0f;          // cluster sums
    if (tid < 1024) {
        out[OFF_NECS + tid] = 0.0f;                      // cluster counts
        const float4* c = reinterpret_cast<const float4*>(cb + tid * 64);
        float s = 0.f;
        #pragma unroll
        for (int j = 0; j < 16; ++j) {
            const float4 v = c[j];
            s += v.x*v.x + v.y*v.y + v.z*v.z + v.w*v.w;
        }
        out[OFF_NCB + tid] = s;                          // ||c_k||^2
    }
    if (tid == 0) out[OFF_LOSS] = 0.0f;                  // SSE accumulator
}

// 512 blocks x 512 threads (8 waves). Block owns 128 rows.
// wave wid: rowgrp = wid>>2 (rows rowgrp*64+lane), quarter q = wid&3
// (codes q*256..q*256+255). Chunk assignment depends ONLY on wid&3, so all
// blocks on a CU walk the same 4 scalar streams -> sL1-hot s_loads (rounds
// 5/6 limiter: 16-32 private streams thrashed the scalar cache, every batch
// at L2 latency, 25% duty/wave). z tile in LDS; 44-VGPR live state (the
// compiler spills any big per-thread array -- rounds 1-4,7 evidence).
__global__ __launch_bounds__(512, 4) void vq_main(const float* __restrict__ z,
                                                  const float* __restrict__ cb,
                                                  const float* __restrict__ cc,
                                                  float* __restrict__ out) {
    const int t    = threadIdx.x;
    const int lane = t & 63;
    const int wid  = t >> 6;
    const int rowgrp = wid >> 2;
    const int q      = wid & 3;
    const int rowbase = blockIdx.x * 128;

    __shared__ float s_zs[128 * 68];     // 34816 B, stride 68 (16B-aligned b128)
    __shared__ float s_cd[4 * 128];      // 2048 B candidate dists (aliased below)
    __shared__ int   s_ci[4 * 128];      // 2048 B candidate idx
    __shared__ int   s_final[128];       // 512 B
    float* s_red = s_cd;                 // SSE reduce reuses s_cd after combine

    // Stage z tile: 128 rows x 16 float4 = 2048 float4s; 4 per thread.
    const float4* zb4 = reinterpret_cast<const float4*>(z) + (size_t)blockIdx.x * 2048;
    #pragma unroll
    for (int j = 0; j < 4; ++j) {
        const int f = t + 512 * j;
        const float4 v = zb4[f];
        const int r  = f >> 4;
        const int d0 = (f & 15) * 4;
        *reinterpret_cast<float4*>(&s_zs[r * 68 + d0]) = v;
    }
    __syncthreads();

    // Wave-uniform code-quarter base in an SGPR.
    const int kbase = __builtin_amdgcn_readfirstlane(q) * 256;
    const int myrow = rowgrp * 64 + lane;

    float bestd = 3.4e38f;
    int   bestk = kbase;
    for (int k0 = kbase; k0 < kbase + 256; k0 += 16) {
        const float* c0 = cb + (size_t)k0 * 64;
        float acc[16];
        #pragma unroll
        for (int j = 0; j < 16; ++j) acc[j] = 0.f;
        #pragma unroll
        for (int dt = 0; dt < 16; ++dt) {
            const float4 zv = *reinterpret_cast<const float4*>(&s_zs[myrow * 68 + dt * 4]);
            #pragma unroll
            for (int j = 0; j < 16; ++j) {   // uniform addr -> s_load batches
                const float4 cv = *reinterpret_cast<const float4*>(c0 + j * 64 + dt * 4);
                acc[j] = fmaf(zv.x, cv.x, acc[j]);
                acc[j] = fmaf(zv.y, cv.y, acc[j]);
                acc[j] = fmaf(zv.z, cv.z, acc[j]);
                acc[j] = fmaf(zv.w, cv.w, acc[j]);
            }
        }
        // score = ||c||^2 - 2*dot (row term constant over k -> same argmin).
        // Ascending code order + strict < == numpy first-min tiebreak.
        #pragma unroll
        for (int j = 0; j < 16; ++j) {
            const float s = fmaf(-2.f, acc[j], cc[k0 + j]);
            if (s < bestd) { bestd = s; bestk = k0 + j; }
        }
    }

    s_cd[q * 128 + myrow] = bestd;
    s_ci[q * 128 + myrow] = bestk;
    __syncthreads();

    // Combine 4 code-quarters per row (quarters ascend in code space).
    if (t < 128) {
        float bd = s_cd[t];
        int   bk = s_ci[t];
        #pragma unroll
        for (int w = 1; w < 4; ++w) {
            const float d = s_cd[w * 128 + t];
            const int   i = s_ci[w * 128 + t];
            if (d < bd) { bd = d; bk = i; }
        }
        s_final[t] = bk;
        out[OFF_IDX + rowbase + t] = (float)bk;
        atomicAdd(&out[OFF_NECS + bk], 1.0f);        // cluster count
    }
    __syncthreads();   // also fences s_cd reads before s_red alias writes

    // Phase 2: z_q write + commitment SSE + cluster-sum atomics.
    // Block tile = 128 rows * 16 float4 = 2048 float4s; 4 per thread.
    float sse = 0.f;
    float4*       qb  = reinterpret_cast<float4*>(out + OFF_ZQ) + (size_t)blockIdx.x * 2048;
    const float4* cb4 = reinterpret_cast<const float4*>(cb);
    #pragma unroll
    for (int j = 0; j < 4; ++j) {
        const int f  = t + 512 * j;
        const int r  = f >> 4;
        const int fc = f & 15;
        const int gk = s_final[r];
        const float4 zv = *reinterpret_cast<const float4*>(&s_zs[r * 68 + fc * 4]);
        const float4 cv = cb4[gk * 16 + fc];
        qb[f] = cv;                      // z_q_st == z_q numerically
        const float e0 = zv.x - cv.x, e1 = zv.y - cv.y;
        const float e2 = zv.z - cv.z, e3 = zv.w - cv.w;
        sse += e0 * e0 + e1 * e1 + e2 * e2 + e3 * e3;
        float* sp = out + OFF_NEW + gk * 64 + fc * 4;
        atomicAdd(sp + 0, zv.x);
        atomicAdd(sp + 1, zv.y);
        atomicAdd(sp + 2, zv.z);
        atomicAdd(sp + 3, zv.w);
    }

    s_red[t] = sse;
    __syncthreads();
    for (int off = 256; off > 0; off >>= 1) {
        if (t < off) s_red[t] += s_red[t + off];
        __syncthreads();
    }
    if (t == 0) atomicAdd(&out[OFF_LOSS], s_red[0]);
}

// One block, 1024 threads: EMA cluster-size update + n-reduction + den table.
__global__ __launch_bounds__(1024) void vq_final_a(const float* __restrict__ ema_cs,
                                                   float* __restrict__ out,
                                                   float* __restrict__ den) {
    const int k = threadIdx.x;
    const float cnt  = out[OFF_NECS + k];
    const float necs = DECAY * ema_cs[k] + ONEM * cnt;

    __shared__ float s_red[1024];
    s_red[k] = necs;
    __syncthreads();
    for (int off = 512; off > 0; off >>= 1) {
        if (k < off) s_red[k] += s_red[k + off];
        __syncthreads();
    }
    const float n = s_red[0];

    out[OFF_NECS + k] = necs;
    den[k] = (necs + EPSV) / (n + (float)KC * EPSV) * n;
    if (k == 0) out[OFF_LOSS] = 0.25f * out[OFF_LOSS] * (1.f / 4194304.f);
}

// 64 blocks x 1024 threads: EMA w update + codebook normalization.
__global__ __launch_bounds__(1024) void vq_final_b(const float* __restrict__ ema_w,
                                                   const float* __restrict__ den,
                                                   float* __restrict__ out) {
    const int e = blockIdx.x * 1024 + threadIdx.x;      // 0..65535, coalesced
    const float s  = out[OFF_NEW + e];                  // raw cluster sum
    const float ew = DECAY * ema_w[e] + ONEM * s;
    out[OFF_NEW + e] = ew;                              // new_ew
    out[OFF_NCB + e] = ew / den[e >> 6];                // new_codebook
}

extern "C" void kernel_launch(void* const* d_in, const int* in_sizes, int n_in,
                              void* d_out, int out_size, void* d_ws, size_t ws_size,
                              hipStream_t stream) {
    const float* z   = (const float*)d_in[0];
    const float* cb  = (const float*)d_in[1];
    const float* ecs = (const float*)d_in[2];
    const float* ew  = (const float*)d_in[3];
    float* out = (float*)d_out;
    float* den = (float*)d_ws;      // 1024 floats of scratch

    vq_prep   <<<256, 256, 0, stream>>>(cb, out);
    vq_main   <<<512, 512, 0, stream>>>(z, cb, out + OFF_NCB, out);
    vq_final_a<<<1,  1024, 0, stream>>>(ecs, out, den);
    vq_final_b<<<64, 1024, 0, stream>>>(ew, den, out);
}